// Round 10
// baseline (245.760 us; speedup 1.0000x reference)
//
#include <hip/hip_runtime.h>
#include <stdint.h>

#define B_    2
#define C_    512
#define NH_   8
#define HD_   64
#define N_    4096
#define G_    32
#define K_    512
#define EPS_  1e-5f
// 0.125 (=1/sqrt(64)) * log2(e): fold softmax scale + exp2 conversion into Q
#define QSCALE_ 0.18033688011112042f

typedef __bf16 bf16;
typedef __attribute__((ext_vector_type(8))) __bf16 bf16x8;
typedef __attribute__((ext_vector_type(4))) float f32x4;

// ============ prep: weight f32->bf16 convert + GroupNorm partial stats ========
__global__ __launch_bounds__(256) void prep_k(const float* __restrict__ qkv_w,
                                              const float* __restrict__ out_w,
                                              const float* __restrict__ x,
                                              bf16* __restrict__ qkvwb,
                                              bf16* __restrict__ outwb,
                                              float* __restrict__ part) {
  const int blk = blockIdx.x;
  const int t = threadIdx.x;
  if (blk < 1024) {
    const int i = blk * 256 + t;
    const int n0 = (3 * C_ * C_) / 4;
    const float* s = (i < n0) ? qkv_w : out_w;
    bf16* d = (i < n0) ? qkvwb : outwb;
    const int k = (i < n0) ? i : i - n0;
    f32x4 v = *reinterpret_cast<const f32x4*>(s + (size_t)k * 4);
    bf16 o[4] = {(bf16)v[0], (bf16)v[1], (bf16)v[2], (bf16)v[3]};
    *reinterpret_cast<uint64_t*>(d + (size_t)k * 4) = *reinterpret_cast<uint64_t*>(o);
  } else {
    const int bb = blk - 1024;
    const float* p = x + (size_t)bb * 16384;
    float s1 = 0.f, s2 = 0.f;
    for (int i = 0; i < 16; ++i) {
      f32x4 v = *reinterpret_cast<const f32x4*>(p + (size_t)(i * 256 + t) * 4);
#pragma unroll
      for (int j = 0; j < 4; ++j) { float f = v[j]; s1 += f; s2 += f * f; }
    }
#pragma unroll
    for (int o = 32; o > 0; o >>= 1) { s1 += __shfl_down(s1, o); s2 += __shfl_down(s2, o); }
    __shared__ float a1[4], a2[4];
    if ((t & 63) == 0) { a1[t >> 6] = s1; a2[t >> 6] = s2; }
    __syncthreads();
    if (t == 0) {
      part[bb * 2]     = a1[0] + a1[1] + a1[2] + a1[3];
      part[bb * 2 + 1] = a2[0] + a2[1] + a2[2] + a2[3];
    }
  }
}

// ======================= GroupNorm apply + transpose =======================
__global__ __launch_bounds__(256) void gn_apply_k(const float* __restrict__ x,
                                                  const float* __restrict__ part,
                                                  const float* __restrict__ gw,
                                                  const float* __restrict__ gb,
                                                  bf16* __restrict__ hT) {
  __shared__ float tile[64][65];
  const int n0 = blockIdx.x * 64, c0 = blockIdx.y * 64, b = blockIdx.z;
  const int t = threadIdx.x;
  {
    const int cc = t >> 2;
    const int nn = (t & 3) * 16;
    const int c = c0 + cc;
    const int bg = b * G_ + (c >> 4);
    float s1 = 0.f, s2 = 0.f;
#pragma unroll
    for (int q = 0; q < 4; ++q) {
      s1 += part[(bg * 4 + q) * 2];
      s2 += part[(bg * 4 + q) * 2 + 1];
    }
    const float mean = s1 * (1.f / 65536.f);
    const float var  = s2 * (1.f / 65536.f) - mean * mean;
    const float rstd = rsqrtf(var + EPS_);
    const float sw = gw[c] * rstd;
    const float sb = gb[c] - mean * sw;
    const float* xp = x + ((size_t)(b * C_ + c)) * N_ + n0 + nn;
#pragma unroll
    for (int q = 0; q < 4; ++q) {
      f32x4 v = *reinterpret_cast<const f32x4*>(xp + q * 4);
#pragma unroll
      for (int j = 0; j < 4; ++j) tile[cc][nn + q * 4 + j] = v[j] * sw + sb;
    }
  }
  __syncthreads();
  {
    const int rn = t >> 2;
    const int ch = (t & 3) * 16;
    bf16* hp = hT + ((size_t)b * N_ + n0 + rn) * C_ + c0 + ch;
    bf16x8 o0, o1;
#pragma unroll
    for (int j = 0; j < 8; ++j) {
      o0[j] = (bf16)tile[ch + j][rn];
      o1[j] = (bf16)tile[ch + 8 + j][rn];
    }
    *reinterpret_cast<bf16x8*>(hp)     = o0;
    *reinterpret_cast<bf16x8*>(hp + 8) = o1;
  }
}

// ======================= GEMM: C[M,N] = A[M,K] * BT[N,K]^T, BK=64 =======================
template <int EPI>
__global__ __launch_bounds__(256) void gemm_bt_k(const bf16* __restrict__ A,
                                                 const bf16* __restrict__ BT,
                                                 const float* __restrict__ bias,
                                                 bf16* __restrict__ out0,
                                                 bf16* __restrict__ out1,
                                                 bf16* __restrict__ out2,
                                                 float* __restrict__ outf,
                                                 const float* __restrict__ xres) {
  __shared__ __align__(16) bf16 As[128][72];   // stride 36 dwords: bank-uniform
  __shared__ __align__(16) bf16 Bs[128][72];
  const int t = threadIdx.x;
  const int w = t >> 6, lane = t & 63;
  const int quad = lane >> 4, l15 = lane & 15;
  const int m0 = blockIdx.y * 128, n0 = blockIdx.x * 128, b = blockIdx.z;
  const bf16* Ab = A + (size_t)m0 * K_;
  const bf16* Bb = BT + ((size_t)b * N_ + n0) * K_;
  const int srow = t >> 1;            // 0..127
  const int sk = (t & 1) * 32;        // 0 or 32 within BK=64

  f32x4 acc[4][4] = {};

  for (int kc = 0; kc < K_ / 64; ++kc) {
    __syncthreads();
    {
      const bf16* ag = Ab + (size_t)srow * K_ + kc * 64 + sk;
      const bf16* bg = Bb + (size_t)srow * K_ + kc * 64 + sk;
#pragma unroll
      for (int c = 0; c < 4; ++c) {
        *reinterpret_cast<bf16x8*>(&As[srow][sk + c * 8]) = *reinterpret_cast<const bf16x8*>(ag + c * 8);
        *reinterpret_cast<bf16x8*>(&Bs[srow][sk + c * 8]) = *reinterpret_cast<const bf16x8*>(bg + c * 8);
      }
    }
    __syncthreads();
    bf16x8 af[4][2], bfv[4][2];
#pragma unroll
    for (int i = 0; i < 4; ++i) {
      af[i][0] = *reinterpret_cast<const bf16x8*>(&As[(w >> 1) * 64 + i * 16 + l15][quad * 8]);
      af[i][1] = *reinterpret_cast<const bf16x8*>(&As[(w >> 1) * 64 + i * 16 + l15][quad * 8 + 32]);
    }
#pragma unroll
    for (int j = 0; j < 4; ++j) {
      bfv[j][0] = *reinterpret_cast<const bf16x8*>(&Bs[(w & 1) * 64 + j * 16 + l15][quad * 8]);
      bfv[j][1] = *reinterpret_cast<const bf16x8*>(&Bs[(w & 1) * 64 + j * 16 + l15][quad * 8 + 32]);
    }
#pragma unroll
    for (int i = 0; i < 4; ++i)
#pragma unroll
      for (int j = 0; j < 4; ++j) {
        acc[i][j] = __builtin_amdgcn_mfma_f32_16x16x32_bf16(af[i][0], bfv[j][0], acc[i][j], 0, 0, 0);
        acc[i][j] = __builtin_amdgcn_mfma_f32_16x16x32_bf16(af[i][1], bfv[j][1], acc[i][j], 0, 0, 0);
      }
  }

  const int rowbase = m0 + (w >> 1) * 64;
  const int colbase = n0 + (w & 1) * 64;
  if (EPI == 0) {
    const int which = m0 >> 9;  // uniform: 128-row block never crosses a 512 boundary
    if (which < 2) {
      bf16* dst = (which == 0) ? out0 : out1;
      const float sc = (which == 0) ? (float)QSCALE_ : 1.0f;
#pragma unroll
      for (int i = 0; i < 4; ++i) {
        const int mbase = rowbase + i * 16 + quad * 4;
        const int head = (mbase >> 6) & 7, d0 = mbase & 63;
        float bi[4];
#pragma unroll
        for (int r = 0; r < 4; ++r) bi[r] = bias[mbase + r];
#pragma unroll
        for (int j = 0; j < 4; ++j) {
          const int n = colbase + j * 16 + l15;
          union { bf16 h[4]; uint64_t u; } pk;
#pragma unroll
          for (int r = 0; r < 4; ++r) pk.h[r] = (bf16)((acc[i][j][r] + bi[r]) * sc);
          *reinterpret_cast<uint64_t*>(dst + ((size_t)(b * NH_ + head) * N_ + n) * HD_ + d0) = pk.u;
        }
      }
    } else {
#pragma unroll
      for (int i = 0; i < 4; ++i) {
        const int mbase = rowbase + i * 16 + quad * 4;
        const int head = (mbase >> 6) & 7;
#pragma unroll
        for (int r = 0; r < 4; ++r) {
          const int d = (mbase + r) & 63;
          const float bi = bias[mbase + r];
#pragma unroll
          for (int j = 0; j < 4; ++j) {
            const int n = colbase + j * 16 + l15;
            out2[((size_t)(b * NH_ + head) * HD_ + d) * N_ + n] = (bf16)(acc[i][j][r] + bi);
          }
        }
      }
    }
  } else {
#pragma unroll
    for (int i = 0; i < 4; ++i) {
#pragma unroll
      for (int r = 0; r < 4; ++r) {
        const int m = rowbase + i * 16 + quad * 4 + r;
        const float bi = bias[m];
#pragma unroll
        for (int j = 0; j < 4; ++j) {
          const int n = colbase + j * 16 + l15;
          const size_t idx = ((size_t)(b * C_ + m)) * N_ + n;
          outf[idx] = acc[i][j][r] + bi + xres[idx];
        }
      }
    }
  }
}

// ===== Flash attention, KEY-SPLIT z=2: 256 thr, 4 waves x 2 bands, 128 q-rows ==
// grid (32, 16, 2): x=rblk (n&31), y=bh, z=key half (keys z*2048..+2048).
// Additive split is exact: no running max (p = exp2(S)); block writes
// UNNORMALIZED acc (bf16, oT layout) to its partial buffer + per-q-row l (f32).
// kf read once per tile feeding both bands' S; vf preloaded to registers and
// reused; band-sequential softmax+PV (one 9216 B P buffer). LDS 46080 B ->
// 3 blocks/CU resident (grid now 1024 = 4/CU worth of blocks; was grid-capped
// at 2). Double-buffered K/V, register prefetch, 1 barrier/tile.
__global__ __launch_bounds__(256, 3) void attn_k(const bf16* __restrict__ qb,
                                                 const bf16* __restrict__ kb,
                                                 const bf16* __restrict__ vb,
                                                 bf16* __restrict__ po0,
                                                 bf16* __restrict__ po1,
                                                 float* __restrict__ pl) {
  __shared__ __align__(16) char smem[46080];
  // K/V buffer b at smem + b*18432 B: K [64 perm][72]; V [64 d][72] at +9216 B
  bf16* Ps = (bf16*)(smem + 36864);    // [4 waves][16][72] (band-sequential)
  bf16* Ot = (bf16*)smem;              // [64 d][136 i] overlay (epilogue)

  const int t = threadIdx.x;
  const int w = t >> 6, lane = t & 63, quad = lane >> 4, l15 = lane & 15;
  const int rblk = blockIdx.x;
  const int bh = blockIdx.y, head = bh & 7, b = bh >> 3;
  const int z = blockIdx.z;
  const bf16* qh = qb + (size_t)bh * N_ * HD_;
  const bf16* kh = kb + (size_t)bh * N_ * HD_ + (size_t)z * 2048 * HD_;
  const bf16* vh = vb + (size_t)bh * HD_ * N_ + (size_t)z * 2048;

  bf16x8 qa[2][2];
#pragma unroll
  for (int b2 = 0; b2 < 2; ++b2) {
    const int bd = w + 4 * b2;
    const bf16* qp = qh + ((size_t)((bd * 16 + l15) * 32 + rblk)) * HD_ + quad * 8;
    qa[b2][0] = *reinterpret_cast<const bf16x8*>(qp);
    qa[b2][1] = *reinterpret_cast<const bf16x8*>(qp + 32);
  }

  f32x4 acc[2][4] = {};
  float lsum[2][4] = {};

  const int sr = t >> 3, sc = (t & 7) * 8;
  const int s0 = (sr & 3) * 16 + (sr >> 2);                 // perm row for key sr
  const int s1 = ((sr + 32) & 3) * 16 + ((sr + 32) >> 2);   // perm row for key sr+32
  bf16* Pw = Ps + w * 1152;

  // preload tile 0 -> buf 0
  {
    *reinterpret_cast<bf16x8*>((bf16*)smem + s0 * 72 + sc) =
        *reinterpret_cast<const bf16x8*>(kh + (size_t)sr * HD_ + sc);
    *reinterpret_cast<bf16x8*>((bf16*)smem + s1 * 72 + sc) =
        *reinterpret_cast<const bf16x8*>(kh + (size_t)(sr + 32) * HD_ + sc);
    bf16* Vb0 = (bf16*)(smem + 9216);
    *reinterpret_cast<bf16x8*>(Vb0 + sr * 72 + sc) =
        *reinterpret_cast<const bf16x8*>(vh + (size_t)sr * N_ + sc);
    *reinterpret_cast<bf16x8*>(Vb0 + (sr + 32) * 72 + sc) =
        *reinterpret_cast<const bf16x8*>(vh + (size_t)(sr + 32) * N_ + sc);
  }
  __syncthreads();

  for (int kt = 0; kt < 32; ++kt) {
    bf16* curK = (bf16*)(smem + (kt & 1) * 18432);
    bf16* curV = (bf16*)(smem + (kt & 1) * 18432 + 9216);

    // prefetch next tile into registers (latency hidden under this tile's compute)
    bf16x8 kr0, kr1, vr0, vr1;
    if (kt != 31) {
      const bf16* kg = kh + ((size_t)(kt + 1) * 64) * HD_;
      kr0 = *reinterpret_cast<const bf16x8*>(kg + (size_t)sr * HD_ + sc);
      kr1 = *reinterpret_cast<const bf16x8*>(kg + (size_t)(sr + 32) * HD_ + sc);
      const bf16* vg = vh + (size_t)(kt + 1) * 64;
      vr0 = *reinterpret_cast<const bf16x8*>(vg + (size_t)sr * N_ + sc);
      vr1 = *reinterpret_cast<const bf16x8*>(vg + (size_t)(sr + 32) * N_ + sc);
    }

    // K fragments: read once, feed both bands' S
    bf16x8 kf0[4], kf1[4];
#pragma unroll
    for (int mt = 0; mt < 4; ++mt) {
      kf0[mt] = *reinterpret_cast<const bf16x8*>(curK + (mt * 16 + l15) * 72 + quad * 8);
      kf1[mt] = *reinterpret_cast<const bf16x8*>(curK + (mt * 16 + l15) * 72 + quad * 8 + 32);
    }
    f32x4 S[2][4];
#pragma unroll
    for (int b2 = 0; b2 < 2; ++b2)
#pragma unroll
      for (int mt = 0; mt < 4; ++mt) {
        f32x4 zz = {0.f, 0.f, 0.f, 0.f};
        zz = __builtin_amdgcn_mfma_f32_16x16x32_bf16(qa[b2][0], kf0[mt], zz, 0, 0, 0);
        S[b2][mt] = __builtin_amdgcn_mfma_f32_16x16x32_bf16(qa[b2][1], kf1[mt], zz, 0, 0, 0);
      }

    // V fragments -> registers (kf now dead), reused by both bands
    bf16x8 vf0[4], vf1[4];
#pragma unroll
    for (int dt = 0; dt < 4; ++dt) {
      vf0[dt] = *reinterpret_cast<const bf16x8*>(curV + (dt * 16 + l15) * 72 + quad * 8);
      vf1[dt] = *reinterpret_cast<const bf16x8*>(curV + (dt * 16 + l15) * 72 + quad * 8 + 32);
    }

    // band-sequential softmax + PV (per-wave P buffer reused across bands)
#pragma unroll
    for (int b2 = 0; b2 < 2; ++b2) {
#pragma unroll
      for (int r = 0; r < 4; ++r) {
        float p0 = __builtin_amdgcn_exp2f(S[b2][0][r]);
        float p1 = __builtin_amdgcn_exp2f(S[b2][1][r]);
        float p2 = __builtin_amdgcn_exp2f(S[b2][2][r]);
        float p3 = __builtin_amdgcn_exp2f(S[b2][3][r]);
        lsum[b2][r] += (p0 + p1) + (p2 + p3);
        union { bf16 h[4]; uint64_t u; } pk;
        pk.h[0] = (bf16)p0; pk.h[1] = (bf16)p1; pk.h[2] = (bf16)p2; pk.h[3] = (bf16)p3;
        *reinterpret_cast<uint64_t*>(Pw + (quad * 4 + r) * 72 + l15 * 4) = pk.u;
      }
      asm volatile("s_waitcnt lgkmcnt(0)" ::: "memory");
      bf16x8 pa0 = *reinterpret_cast<const bf16x8*>(Pw + l15 * 72 + quad * 8);
      bf16x8 pa1 = *reinterpret_cast<const bf16x8*>(Pw + l15 * 72 + quad * 8 + 32);
#pragma unroll
      for (int dt = 0; dt < 4; ++dt) {
        acc[b2][dt] = __builtin_amdgcn_mfma_f32_16x16x32_bf16(pa0, vf0[dt], acc[b2][dt], 0, 0, 0);
        acc[b2][dt] = __builtin_amdgcn_mfma_f32_16x16x32_bf16(pa1, vf1[dt], acc[b2][dt], 0, 0, 0);
      }
    }

    // stage prefetched tile into the alternate buffer
    if (kt != 31) {
      bf16* nK = (bf16*)(smem + ((kt + 1) & 1) * 18432);
      bf16* nV = (bf16*)(smem + ((kt + 1) & 1) * 18432 + 9216);
      *reinterpret_cast<bf16x8*>(nK + s0 * 72 + sc) = kr0;
      *reinterpret_cast<bf16x8*>(nK + s1 * 72 + sc) = kr1;
      *reinterpret_cast<bf16x8*>(nV + sr * 72 + sc) = vr0;
      *reinterpret_cast<bf16x8*>(nV + (sr + 32) * 72 + sc) = vr1;
    }
    __syncthreads();
  }

  // l reduction across the 16 lanes sharing each q row; write partial l
  bf16* po = (z == 0) ? po0 : po1;
#pragma unroll
  for (int b2 = 0; b2 < 2; ++b2) {
    const int bd = w + 4 * b2;
#pragma unroll
    for (int r = 0; r < 4; ++r) {
      float l = lsum[b2][r];
#pragma unroll
      for (int o = 1; o < 16; o <<= 1) l += __shfl_xor(l, o);
      if (l15 == 0)
        pl[((size_t)z * 16 + bh) * N_ + (bd * 16 + quad * 4 + r) * 32 + rblk] = l;
    }
  }

  // epilogue: UNNORMALIZED acc -> Ot overlay [64 d][136 i] -> coalesced stores
#pragma unroll
  for (int b2 = 0; b2 < 2; ++b2) {
    const int bd = w + 4 * b2;
#pragma unroll
    for (int dt = 0; dt < 4; ++dt) {
      union { bf16 h[4]; uint64_t u; } o4;
#pragma unroll
      for (int r = 0; r < 4; ++r) o4.h[r] = (bf16)acc[b2][dt][r];
      *reinterpret_cast<uint64_t*>(Ot + (dt * 16 + l15) * 136 + bd * 16 + quad * 4) = o4.u;
    }
  }
  __syncthreads();
  {
    // po[b'][n'][c']: b'=head>>2, n' = rblk*128 + b*64 + d, c' = (head&3)*128 + i
    const int d = t >> 2, ic = (t & 3) * 32;
    bf16* op = po + (size_t)(head >> 2) * N_ * C_ +
               ((size_t)(rblk * 128 + b * 64 + d)) * C_ + (head & 3) * 128 + ic;
#pragma unroll
    for (int c = 0; c < 4; ++c)
      *reinterpret_cast<bf16x8*>(op + c * 8) =
          *reinterpret_cast<const bf16x8*>(Ot + d * 136 + ic + c * 8);
  }
}

// ======= combine: oT = (a0 + a1) / (l0 + l1), elementwise over oT layout ======
__global__ __launch_bounds__(256) void comb_k(const bf16* __restrict__ a0,
                                              const bf16* __restrict__ a1,
                                              const float* __restrict__ pl,
                                              bf16* __restrict__ oT) {
  const int tid = blockIdx.x * 256 + threadIdx.x;
  const int e8 = tid * 8;                 // e = b'*2^21 + n'*2^9 + c'
  const int cp = e8 & 511;
  const int np = (e8 >> 9) & 4095;
  const int bp = e8 >> 21;
  const int head = (bp << 2) | (cp >> 7);
  const int rblk = np >> 7;
  const int b = (np >> 6) & 1;
  const int bh = b * NH_ + head;
  const int ibase = cp & 127;
  const float* l0 = pl + (size_t)bh * N_ + rblk;
  const float* l1 = l0 + (size_t)16 * N_;
  bf16x8 x0 = *reinterpret_cast<const bf16x8*>(a0 + e8);
  bf16x8 x1 = *reinterpret_cast<const bf16x8*>(a1 + e8);
  bf16x8 o;
#pragma unroll
  for (int j = 0; j < 8; ++j) {
    const int off = (ibase + j) * 32;
    const float l = l0[off] + l1[off];
    o[j] = (bf16)(((float)x0[j] + (float)x1[j]) * __builtin_amdgcn_rcpf(l));
  }
  *reinterpret_cast<bf16x8*>(oT + e8) = o;
}

// ======================= launch =======================
extern "C" void kernel_launch(void* const* d_in, const int* in_sizes, int n_in,
                              void* d_out, int out_size, void* d_ws, size_t ws_size,
                              hipStream_t stream) {
  const float* x     = (const float*)d_in[0];
  const float* gn_w  = (const float*)d_in[1];
  const float* gn_b  = (const float*)d_in[2];
  const float* qkv_w = (const float*)d_in[3];
  const float* qkv_b = (const float*)d_in[4];
  const float* out_w = (const float*)d_in[5];
  const float* out_b = (const float*)d_in[6];
  float* out = (float*)d_out;

  char* ws = (char*)d_ws;
  const size_t SZ = (size_t)B_ * C_ * N_ * sizeof(bf16);  // 8.4 MB per bf16 buffer
  float* part  = (float*)ws;                  // 2 KB partial stats
  bf16* hT    = (bf16*)(ws + 4096);           // [B][N][C]; reused as attn partial 0
  bf16* qbuf  = (bf16*)(ws + 4096 + SZ);      // [B*NH][N][HD]
  bf16* kbuf  = (bf16*)(ws + 4096 + 2 * SZ);  // [B*NH][N][HD]
  bf16* vbuf  = (bf16*)(ws + 4096 + 3 * SZ);  // [B*NH][HD][N]
  bf16* oT    = (bf16*)(ws + 4096 + 4 * SZ);  // [B'][N'][C'] combined output
  bf16* qkvwb = (bf16*)(ws + 4096 + 5 * SZ);  // [1536][512] bf16
  bf16* outwb = qkvwb + (size_t)3 * C_ * C_;  // [512][512] bf16
  bf16* po1   = outwb + (size_t)C_ * C_;      // attn partial 1 (8.4 MB)
  float* pL   = (float*)(po1 + (size_t)B_ * C_ * N_);  // [2][16][4096] f32

  prep_k<<<dim3(1280), dim3(256), 0, stream>>>(qkv_w, out_w, x, qkvwb, outwb, part);
  gn_apply_k<<<dim3(N_ / 64, C_ / 64, B_), dim3(256), 0, stream>>>(x, part, gn_w, gn_b, hT);
  gemm_bt_k<0><<<dim3(N_ / 128, (3 * C_) / 128, B_), dim3(256), 0, stream>>>(
      qkvwb, hT, qkv_b, qbuf, kbuf, vbuf, nullptr, nullptr);
  attn_k<<<dim3(32, B_ * NH_, 2), dim3(256), 0, stream>>>(qbuf, kbuf, vbuf, hT, po1, pL);
  comb_k<<<dim3((B_ * C_ * N_) / 2048), dim3(256), 0, stream>>>(hT, po1, pL, oT);
  gemm_bt_k<1><<<dim3(N_ / 128, C_ / 128, B_), dim3(256), 0, stream>>>(
      outwb, oT, out_b, nullptr, nullptr, nullptr, out, x);
}

// Round 11
// 203.772 us; speedup vs baseline: 1.2061x; 1.2061x over previous
//
#include <hip/hip_runtime.h>
#include <stdint.h>

#define B_    2
#define C_    512
#define NH_   8
#define HD_   64
#define N_    4096
#define G_    32
#define K_    512
#define EPS_  1e-5f
// 0.125 (=1/sqrt(64)) * log2(e): fold softmax scale + exp2 conversion into Q
#define QSCALE_ 0.18033688011112042f

typedef __bf16 bf16;
typedef __attribute__((ext_vector_type(8))) __bf16 bf16x8;
typedef __attribute__((ext_vector_type(4))) float f32x4;

// ============ prep: weight f32->bf16 convert + GroupNorm partial stats ========
__global__ __launch_bounds__(256) void prep_k(const float* __restrict__ qkv_w,
                                              const float* __restrict__ out_w,
                                              const float* __restrict__ x,
                                              bf16* __restrict__ qkvwb,
                                              bf16* __restrict__ outwb,
                                              float* __restrict__ part) {
  const int blk = blockIdx.x;
  const int t = threadIdx.x;
  if (blk < 1024) {
    const int i = blk * 256 + t;
    const int n0 = (3 * C_ * C_) / 4;
    const float* s = (i < n0) ? qkv_w : out_w;
    bf16* d = (i < n0) ? qkvwb : outwb;
    const int k = (i < n0) ? i : i - n0;
    f32x4 v = *reinterpret_cast<const f32x4*>(s + (size_t)k * 4);
    bf16 o[4] = {(bf16)v[0], (bf16)v[1], (bf16)v[2], (bf16)v[3]};
    *reinterpret_cast<uint64_t*>(d + (size_t)k * 4) = *reinterpret_cast<uint64_t*>(o);
  } else {
    const int bb = blk - 1024;
    const float* p = x + (size_t)bb * 16384;
    float s1 = 0.f, s2 = 0.f;
    for (int i = 0; i < 16; ++i) {
      f32x4 v = *reinterpret_cast<const f32x4*>(p + (size_t)(i * 256 + t) * 4);
#pragma unroll
      for (int j = 0; j < 4; ++j) { float f = v[j]; s1 += f; s2 += f * f; }
    }
#pragma unroll
    for (int o = 32; o > 0; o >>= 1) { s1 += __shfl_down(s1, o); s2 += __shfl_down(s2, o); }
    __shared__ float a1[4], a2[4];
    if ((t & 63) == 0) { a1[t >> 6] = s1; a2[t >> 6] = s2; }
    __syncthreads();
    if (t == 0) {
      part[bb * 2]     = a1[0] + a1[1] + a1[2] + a1[3];
      part[bb * 2 + 1] = a2[0] + a2[1] + a2[2] + a2[3];
    }
  }
}

// ======================= GroupNorm apply + transpose =======================
__global__ __launch_bounds__(256) void gn_apply_k(const float* __restrict__ x,
                                                  const float* __restrict__ part,
                                                  const float* __restrict__ gw,
                                                  const float* __restrict__ gb,
                                                  bf16* __restrict__ hT) {
  __shared__ float tile[64][65];
  const int n0 = blockIdx.x * 64, c0 = blockIdx.y * 64, b = blockIdx.z;
  const int t = threadIdx.x;
  {
    const int cc = t >> 2;
    const int nn = (t & 3) * 16;
    const int c = c0 + cc;
    const int bg = b * G_ + (c >> 4);
    float s1 = 0.f, s2 = 0.f;
#pragma unroll
    for (int q = 0; q < 4; ++q) {
      s1 += part[(bg * 4 + q) * 2];
      s2 += part[(bg * 4 + q) * 2 + 1];
    }
    const float mean = s1 * (1.f / 65536.f);
    const float var  = s2 * (1.f / 65536.f) - mean * mean;
    const float rstd = rsqrtf(var + EPS_);
    const float sw = gw[c] * rstd;
    const float sb = gb[c] - mean * sw;
    const float* xp = x + ((size_t)(b * C_ + c)) * N_ + n0 + nn;
#pragma unroll
    for (int q = 0; q < 4; ++q) {
      f32x4 v = *reinterpret_cast<const f32x4*>(xp + q * 4);
#pragma unroll
      for (int j = 0; j < 4; ++j) tile[cc][nn + q * 4 + j] = v[j] * sw + sb;
    }
  }
  __syncthreads();
  {
    const int rn = t >> 2;
    const int ch = (t & 3) * 16;
    bf16* hp = hT + ((size_t)b * N_ + n0 + rn) * C_ + c0 + ch;
    bf16x8 o0, o1;
#pragma unroll
    for (int j = 0; j < 8; ++j) {
      o0[j] = (bf16)tile[ch + j][rn];
      o1[j] = (bf16)tile[ch + 8 + j][rn];
    }
    *reinterpret_cast<bf16x8*>(hp)     = o0;
    *reinterpret_cast<bf16x8*>(hp + 8) = o1;
  }
}

// ======================= GEMM: C[M,N] = A[M,K] * BT[N,K]^T, BK=64 =======================
template <int EPI>
__global__ __launch_bounds__(256) void gemm_bt_k(const bf16* __restrict__ A,
                                                 const bf16* __restrict__ BT,
                                                 const float* __restrict__ bias,
                                                 bf16* __restrict__ out0,
                                                 bf16* __restrict__ out1,
                                                 bf16* __restrict__ out2,
                                                 float* __restrict__ outf,
                                                 const float* __restrict__ xres) {
  __shared__ __align__(16) bf16 As[128][72];   // stride 36 dwords: bank-uniform
  __shared__ __align__(16) bf16 Bs[128][72];
  const int t = threadIdx.x;
  const int w = t >> 6, lane = t & 63;
  const int quad = lane >> 4, l15 = lane & 15;
  const int m0 = blockIdx.y * 128, n0 = blockIdx.x * 128, b = blockIdx.z;
  const bf16* Ab = A + (size_t)m0 * K_;
  const bf16* Bb = BT + ((size_t)b * N_ + n0) * K_;
  const int srow = t >> 1;            // 0..127
  const int sk = (t & 1) * 32;        // 0 or 32 within BK=64

  f32x4 acc[4][4] = {};

  for (int kc = 0; kc < K_ / 64; ++kc) {
    __syncthreads();
    {
      const bf16* ag = Ab + (size_t)srow * K_ + kc * 64 + sk;
      const bf16* bg = Bb + (size_t)srow * K_ + kc * 64 + sk;
#pragma unroll
      for (int c = 0; c < 4; ++c) {
        *reinterpret_cast<bf16x8*>(&As[srow][sk + c * 8]) = *reinterpret_cast<const bf16x8*>(ag + c * 8);
        *reinterpret_cast<bf16x8*>(&Bs[srow][sk + c * 8]) = *reinterpret_cast<const bf16x8*>(bg + c * 8);
      }
    }
    __syncthreads();
    bf16x8 af[4][2], bfv[4][2];
#pragma unroll
    for (int i = 0; i < 4; ++i) {
      af[i][0] = *reinterpret_cast<const bf16x8*>(&As[(w >> 1) * 64 + i * 16 + l15][quad * 8]);
      af[i][1] = *reinterpret_cast<const bf16x8*>(&As[(w >> 1) * 64 + i * 16 + l15][quad * 8 + 32]);
    }
#pragma unroll
    for (int j = 0; j < 4; ++j) {
      bfv[j][0] = *reinterpret_cast<const bf16x8*>(&Bs[(w & 1) * 64 + j * 16 + l15][quad * 8]);
      bfv[j][1] = *reinterpret_cast<const bf16x8*>(&Bs[(w & 1) * 64 + j * 16 + l15][quad * 8 + 32]);
    }
#pragma unroll
    for (int i = 0; i < 4; ++i)
#pragma unroll
      for (int j = 0; j < 4; ++j) {
        acc[i][j] = __builtin_amdgcn_mfma_f32_16x16x32_bf16(af[i][0], bfv[j][0], acc[i][j], 0, 0, 0);
        acc[i][j] = __builtin_amdgcn_mfma_f32_16x16x32_bf16(af[i][1], bfv[j][1], acc[i][j], 0, 0, 0);
      }
  }

  const int rowbase = m0 + (w >> 1) * 64;
  const int colbase = n0 + (w & 1) * 64;
  if (EPI == 0) {
    const int which = m0 >> 9;  // uniform: 128-row block never crosses a 512 boundary
    if (which < 2) {
      bf16* dst = (which == 0) ? out0 : out1;
      const float sc = (which == 0) ? (float)QSCALE_ : 1.0f;
#pragma unroll
      for (int i = 0; i < 4; ++i) {
        const int mbase = rowbase + i * 16 + quad * 4;
        const int head = (mbase >> 6) & 7, d0 = mbase & 63;
        float bi[4];
#pragma unroll
        for (int r = 0; r < 4; ++r) bi[r] = bias[mbase + r];
#pragma unroll
        for (int j = 0; j < 4; ++j) {
          const int n = colbase + j * 16 + l15;
          union { bf16 h[4]; uint64_t u; } pk;
#pragma unroll
          for (int r = 0; r < 4; ++r) pk.h[r] = (bf16)((acc[i][j][r] + bi[r]) * sc);
          *reinterpret_cast<uint64_t*>(dst + ((size_t)(b * NH_ + head) * N_ + n) * HD_ + d0) = pk.u;
        }
      }
    } else {
#pragma unroll
      for (int i = 0; i < 4; ++i) {
        const int mbase = rowbase + i * 16 + quad * 4;
        const int head = (mbase >> 6) & 7;
#pragma unroll
        for (int r = 0; r < 4; ++r) {
          const int d = (mbase + r) & 63;
          const float bi = bias[mbase + r];
#pragma unroll
          for (int j = 0; j < 4; ++j) {
            const int n = colbase + j * 16 + l15;
            out2[((size_t)(b * NH_ + head) * HD_ + d) * N_ + n] = (bf16)(acc[i][j][r] + bi);
          }
        }
      }
    }
  } else {
#pragma unroll
    for (int i = 0; i < 4; ++i) {
#pragma unroll
      for (int r = 0; r < 4; ++r) {
        const int m = rowbase + i * 16 + quad * 4 + r;
        const float bi = bias[m];
#pragma unroll
        for (int j = 0; j < 4; ++j) {
          const int n = colbase + j * 16 + l15;
          const size_t idx = ((size_t)(b * C_ + m)) * N_ + n;
          outf[idx] = acc[i][j][r] + bi + xres[idx];
        }
      }
    }
  }
}

// ===== Flash attention, TRANSPOSED MFMAs (no P round-trip through LDS) ========
// grid (32, 16): x=rblk (n&31), y=bh. 4 waves x 2 bands = 128 q-rows/block.
// S^T = mfma(A=Kperm, B=Q): lane holds P[query=l15][16 keys]. K staging perm
// p(a) = [a5, a2, a4a3, a1a0] makes those 16 keys EXACTLY the lane's PV
// B-operand fragment (k = quad*8+j per 32-key MFMA) -> P stays in registers.
// O^T = mfma(A=V(d-major), B=P): acc has q=l15, d=quad*4+r (+16*dt).
// No running max (scores tiny): p = exp2(S), l deferred (2 shuffles/band).
// LDS: only K/V double-buffer (36864 B), 1 barrier/tile, register prefetch.
__global__ __launch_bounds__(256, 2) void attn_k(const bf16* __restrict__ qb,
                                                 const bf16* __restrict__ kb,
                                                 const bf16* __restrict__ vb,
                                                 bf16* __restrict__ oT) {
  __shared__ __align__(16) char smem[36864];
  // buffer b at smem + b*18432 B: K [64 perm][72]; V [64 d][72] at +9216 B
  bf16* Ot = (bf16*)smem;              // [128 i][72 d] overlay (epilogue)

  const int t = threadIdx.x;
  const int w = t >> 6, lane = t & 63, quad = lane >> 4, l15 = lane & 15;
  const int rblk = blockIdx.x;
  const int bh = blockIdx.y, head = bh & 7, b = bh >> 3;
  const bf16* qh = qb + (size_t)bh * N_ * HD_;
  const bf16* kh = kb + (size_t)bh * N_ * HD_;
  const bf16* vh = vb + (size_t)bh * HD_ * N_;

  bf16x8 qa[2][2];
#pragma unroll
  for (int b2 = 0; b2 < 2; ++b2) {
    const int bd = w + 4 * b2;
    const bf16* qp = qh + ((size_t)((bd * 16 + l15) * 32 + rblk)) * HD_ + quad * 8;
    qa[b2][0] = *reinterpret_cast<const bf16x8*>(qp);
    qa[b2][1] = *reinterpret_cast<const bf16x8*>(qp + 32);
  }

  f32x4 acc[2][4] = {};
  float lsum[2] = {0.f, 0.f};

  const int sr = t >> 3, sc = (t & 7) * 8;
  // perm: key a -> row ((a>>2)&1)*16 + ((a>>3)&3)*4 + (a&3); rows for a and a+32
  // differ only in bit5 -> s1 = s0 + 32.
  const int s0 = ((sr >> 2) & 1) * 16 + ((sr >> 3) & 3) * 4 + (sr & 3);
  const int s1 = s0 + 32;

  // preload tile 0 -> buf 0
  {
    *reinterpret_cast<bf16x8*>((bf16*)smem + s0 * 72 + sc) =
        *reinterpret_cast<const bf16x8*>(kh + (size_t)sr * HD_ + sc);
    *reinterpret_cast<bf16x8*>((bf16*)smem + s1 * 72 + sc) =
        *reinterpret_cast<const bf16x8*>(kh + (size_t)(sr + 32) * HD_ + sc);
    bf16* Vb0 = (bf16*)(smem + 9216);
    *reinterpret_cast<bf16x8*>(Vb0 + sr * 72 + sc) =
        *reinterpret_cast<const bf16x8*>(vh + (size_t)sr * N_ + sc);
    *reinterpret_cast<bf16x8*>(Vb0 + (sr + 32) * 72 + sc) =
        *reinterpret_cast<const bf16x8*>(vh + (size_t)(sr + 32) * N_ + sc);
  }
  __syncthreads();

  for (int kt = 0; kt < 64; ++kt) {
    bf16* curK = (bf16*)(smem + (kt & 1) * 18432);
    bf16* curV = (bf16*)(smem + (kt & 1) * 18432 + 9216);

    // prefetch next tile into registers (latency hidden under this tile's compute)
    bf16x8 kr0, kr1, vr0, vr1;
    if (kt != 63) {
      const bf16* kg = kh + ((size_t)(kt + 1) * 64) * HD_;
      kr0 = *reinterpret_cast<const bf16x8*>(kg + (size_t)sr * HD_ + sc);
      kr1 = *reinterpret_cast<const bf16x8*>(kg + (size_t)(sr + 32) * HD_ + sc);
      const bf16* vg = vh + (size_t)(kt + 1) * 64;
      vr0 = *reinterpret_cast<const bf16x8*>(vg + (size_t)sr * N_ + sc);
      vr1 = *reinterpret_cast<const bf16x8*>(vg + (size_t)(sr + 32) * N_ + sc);
    }

    // K fragments (A-operand) read once, feed both bands' S^T
    bf16x8 kf0[4], kf1[4];
#pragma unroll
    for (int mt = 0; mt < 4; ++mt) {
      kf0[mt] = *reinterpret_cast<const bf16x8*>(curK + (mt * 16 + l15) * 72 + quad * 8);
      kf1[mt] = *reinterpret_cast<const bf16x8*>(curK + (mt * 16 + l15) * 72 + quad * 8 + 32);
    }
    f32x4 S[2][4];
#pragma unroll
    for (int b2 = 0; b2 < 2; ++b2)
#pragma unroll
      for (int mt = 0; mt < 4; ++mt) {
        f32x4 zz = {0.f, 0.f, 0.f, 0.f};
        zz = __builtin_amdgcn_mfma_f32_16x16x32_bf16(kf0[mt], qa[b2][0], zz, 0, 0, 0);
        S[b2][mt] = __builtin_amdgcn_mfma_f32_16x16x32_bf16(kf1[mt], qa[b2][1], zz, 0, 0, 0);
      }

    // V fragments (A-operand, kf now dead), reused by both bands
    bf16x8 vf0[4], vf1[4];
#pragma unroll
    for (int dt = 0; dt < 4; ++dt) {
      vf0[dt] = *reinterpret_cast<const bf16x8*>(curV + (dt * 16 + l15) * 72 + quad * 8);
      vf1[dt] = *reinterpret_cast<const bf16x8*>(curV + (dt * 16 + l15) * 72 + quad * 8 + 32);
    }

    // exp2 + pack P fragments IN REGISTERS, then PV
#pragma unroll
    for (int b2 = 0; b2 < 2; ++b2) {
      union { bf16 h[8]; bf16x8 v; } f0, f1;
      float s = 0.f;
#pragma unroll
      for (int r = 0; r < 4; ++r) {
        float p0 = __builtin_amdgcn_exp2f(S[b2][0][r]);
        float p1 = __builtin_amdgcn_exp2f(S[b2][1][r]);
        float p2 = __builtin_amdgcn_exp2f(S[b2][2][r]);
        float p3 = __builtin_amdgcn_exp2f(S[b2][3][r]);
        s += (p0 + p1) + (p2 + p3);
        f0.h[r] = (bf16)p0; f0.h[4 + r] = (bf16)p1;   // keys quad*8+r, quad*8+4+r
        f1.h[r] = (bf16)p2; f1.h[4 + r] = (bf16)p3;   // keys 32+quad*8+r, +4+r
      }
      lsum[b2] += s;
#pragma unroll
      for (int dt = 0; dt < 4; ++dt) {
        acc[b2][dt] = __builtin_amdgcn_mfma_f32_16x16x32_bf16(vf0[dt], f0.v, acc[b2][dt], 0, 0, 0);
        acc[b2][dt] = __builtin_amdgcn_mfma_f32_16x16x32_bf16(vf1[dt], f1.v, acc[b2][dt], 0, 0, 0);
      }
    }

    // stage prefetched tile into the alternate buffer
    if (kt != 63) {
      bf16* nK = (bf16*)(smem + ((kt + 1) & 1) * 18432);
      bf16* nV = (bf16*)(smem + ((kt + 1) & 1) * 18432 + 9216);
      *reinterpret_cast<bf16x8*>(nK + s0 * 72 + sc) = kr0;
      *reinterpret_cast<bf16x8*>(nK + s1 * 72 + sc) = kr1;
      *reinterpret_cast<bf16x8*>(nV + sr * 72 + sc) = vr0;
      *reinterpret_cast<bf16x8*>(nV + (sr + 32) * 72 + sc) = vr1;
    }
    __syncthreads();
  }

  // l reduction: lane owns query l15 fully per quad; combine the 4 quads
  float inv[2];
#pragma unroll
  for (int b2 = 0; b2 < 2; ++b2) {
    float l = lsum[b2];
    l += __shfl_xor(l, 16);
    l += __shfl_xor(l, 32);
    inv[b2] = 1.f / l;
  }

  // epilogue: acc (q=l15, d=dt*16+quad*4+r) -> Ot [128 i][72 d] via b64 writes
#pragma unroll
  for (int b2 = 0; b2 < 2; ++b2) {
    const int i = (w + 4 * b2) * 16 + l15;
#pragma unroll
    for (int dt = 0; dt < 4; ++dt) {
      union { bf16 h[4]; uint64_t u; } o4;
#pragma unroll
      for (int r = 0; r < 4; ++r) o4.h[r] = (bf16)(acc[b2][dt][r] * inv[b2]);
      *reinterpret_cast<uint64_t*>(Ot + i * 72 + dt * 16 + quad * 4) = o4.u;
    }
  }
  __syncthreads();
  {
    // oT[b'][n'][c']: b'=head>>2, n' = rblk*128 + b*64 + d, c' = (head&3)*128 + i
    const int d = t >> 2, ic = (t & 3) * 32;
    bf16* op = oT + (size_t)(head >> 2) * N_ * C_ +
               ((size_t)(rblk * 128 + b * 64 + d)) * C_ + (head & 3) * 128 + ic;
#pragma unroll
    for (int c = 0; c < 4; ++c) {
      union { bf16 h[8]; bf16x8 v; } o8;
#pragma unroll
      for (int j = 0; j < 8; ++j) o8.h[j] = Ot[(ic + c * 8 + j) * 72 + d];
      *reinterpret_cast<bf16x8*>(op + c * 8) = o8.v;
    }
  }
}

// ======================= launch =======================
extern "C" void kernel_launch(void* const* d_in, const int* in_sizes, int n_in,
                              void* d_out, int out_size, void* d_ws, size_t ws_size,
                              hipStream_t stream) {
  const float* x     = (const float*)d_in[0];
  const float* gn_w  = (const float*)d_in[1];
  const float* gn_b  = (const float*)d_in[2];
  const float* qkv_w = (const float*)d_in[3];
  const float* qkv_b = (const float*)d_in[4];
  const float* out_w = (const float*)d_in[5];
  const float* out_b = (const float*)d_in[6];
  float* out = (float*)d_out;

  char* ws = (char*)d_ws;
  const size_t SZ = (size_t)B_ * C_ * N_ * sizeof(bf16);  // 8.4 MB per bf16 buffer
  float* part  = (float*)ws;                  // 2 KB partial stats
  bf16* hT    = (bf16*)(ws + 4096);           // [B][N][C]
  bf16* qbuf  = (bf16*)(ws + 4096 + SZ);      // [B*NH][N][HD]
  bf16* kbuf  = (bf16*)(ws + 4096 + 2 * SZ);  // [B*NH][N][HD]
  bf16* vbuf  = (bf16*)(ws + 4096 + 3 * SZ);  // [B*NH][HD][N]
  bf16* oT    = (bf16*)(ws + 4096 + 4 * SZ);  // [B'][N'][C'] scrambled-transposed
  bf16* qkvwb = (bf16*)(ws + 4096 + 5 * SZ);  // [1536][512] bf16
  bf16* outwb = qkvwb + (size_t)3 * C_ * C_;  // [512][512] bf16

  prep_k<<<dim3(1280), dim3(256), 0, stream>>>(qkv_w, out_w, x, qkvwb, outwb, part);
  gn_apply_k<<<dim3(N_ / 64, C_ / 64, B_), dim3(256), 0, stream>>>(x, part, gn_w, gn_b, hT);
  gemm_bt_k<0><<<dim3(N_ / 128, (3 * C_) / 128, B_), dim3(256), 0, stream>>>(
      qkvwb, hT, qkv_b, qbuf, kbuf, vbuf, nullptr, nullptr);
  attn_k<<<dim3(32, B_ * NH_), dim3(256), 0, stream>>>(qbuf, kbuf, vbuf, oT);
  gemm_bt_k<1><<<dim3(N_ / 128, C_ / 128, B_), dim3(256), 0, stream>>>(
      outwb, oT, out_b, nullptr, nullptr, nullptr, out, x);
}